// Round 6
// baseline (592.360 us; speedup 1.0000x reference)
//
#include <hip/hip_runtime.h>
#include <math.h>

#define N_NODES 50000
#define N_EDGES 800000
#define CDIM    128
#define GDIM    128
#define L0DIM   512
#define L1DIM   256

typedef unsigned int uint;
typedef unsigned short ushort;
typedef __attribute__((ext_vector_type(8))) short short8;
typedef __attribute__((ext_vector_type(4))) float f32x4;

__device__ inline ushort f2bf(float f) {
  uint u = __float_as_uint(f);
  uint r = (u + 0x7fffu + ((u >> 16) & 1u)) >> 16;
  return (ushort)r;
}
__device__ inline float bflo(uint u) { return __uint_as_float(u << 16); }
__device__ inline float bfhi(uint u) { return __uint_as_float(u & 0xffff0000u); }

// ============================ CSR build =================================
__global__ void hist_kernel(const int* __restrict__ dst, int* counts, int E) {
  int e = blockIdx.x * 256 + threadIdx.x;
  if (e < E) atomicAdd(&counts[dst[e]], 1);
}

__global__ void scan_blocks(const int* __restrict__ counts, int* excl, int* bsums, int N) {
  __shared__ int s[1024];
  int tid = threadIdx.x;
  int i = blockIdx.x * 1024 + tid;
  int v = (i < N) ? counts[i] : 0;
  s[tid] = v;
  __syncthreads();
  for (int off = 1; off < 1024; off <<= 1) {
    int t = (tid >= off) ? s[tid - off] : 0;
    __syncthreads();
    s[tid] += t;
    __syncthreads();
  }
  if (i < N) excl[i] = s[tid] - v;
  if (tid == 1023) bsums[blockIdx.x] = s[1023];
}

__global__ void scan_sums(int* bsums, int nb) {
  int lane = threadIdx.x;  // 64
  int orig = (lane < nb) ? bsums[lane] : 0;
  int v = orig;
#pragma unroll
  for (int off = 1; off < 64; off <<= 1) {
    int t = __shfl_up(v, off);
    if (lane >= off) v += t;
  }
  if (lane < nb) bsums[lane] = v - orig;  // exclusive
}

__global__ void scan_add(const int* __restrict__ excl, const int* __restrict__ bsums,
                         int* indptr, int N, int E) {
  int i = blockIdx.x * 1024 + threadIdx.x;
  if (i < N) indptr[i] = excl[i] + bsums[blockIdx.x];
  if (i == 0) indptr[N] = E;
}

__global__ void scatter2_kernel(const int* __restrict__ dst, const int* __restrict__ src,
                                const float* __restrict__ attr,
                                const int* __restrict__ indptr,
                                int* cursor, int* csr_src, float4* csr_attr, int E) {
  int e = blockIdx.x * 256 + threadIdx.x;
  if (e < E) {
    int d = dst[e];
    int pos = atomicAdd(&cursor[d], 1);
    int i = indptr[d] + pos;
    csr_src[i] = src[e];
    csr_attr[i] = make_float4(attr[e * 3 + 0], attr[e * 3 + 1], attr[e * 3 + 2], 0.f);
  }
}

// ===================== layer 0 (din=4) q/kv/skip ========================
__global__ void l0_qkvs(const float* __restrict__ x,
                        const float* __restrict__ Wq, const float* __restrict__ bq,
                        const float* __restrict__ Wk, const float* __restrict__ bk,
                        const float* __restrict__ Wv, const float* __restrict__ bv,
                        const float* __restrict__ Ws, const float* __restrict__ bs,
                        float* __restrict__ q, ushort* __restrict__ kvb,
                        float* __restrict__ hs, int N) {
  __shared__ float W[4][4][128];
  __shared__ float B[4][128];
  int tid = threadIdx.x;
  for (int i = tid; i < 4 * 128; i += 256) {
    W[0][i >> 7][i & 127] = Wq[i];
    W[1][i >> 7][i & 127] = Wk[i];
    W[2][i >> 7][i & 127] = Wv[i];
    W[3][i >> 7][i & 127] = Ws[i];
  }
  for (int i = tid; i < 128; i += 256) {
    B[0][i] = bq[i]; B[1][i] = bk[i]; B[2][i] = bv[i]; B[3][i] = bs[i];
  }
  __syncthreads();
  int gid = blockIdx.x * 256 + tid;
  int n = gid >> 7, c = gid & 127;
  if (n >= N) return;
  float x0 = x[n * 4 + 0], x1 = x[n * 4 + 1], x2 = x[n * 4 + 2], x3 = x[n * 4 + 3];
  float qv = x0 * W[0][0][c] + x1 * W[0][1][c] + x2 * W[0][2][c] + x3 * W[0][3][c] + B[0][c];
  float kv = x0 * W[1][0][c] + x1 * W[1][1][c] + x2 * W[1][2][c] + x3 * W[1][3][c] + B[1][c];
  float vv = x0 * W[2][0][c] + x1 * W[2][1][c] + x2 * W[2][2][c] + x3 * W[2][3][c] + B[2][c];
  float sv = x0 * W[3][0][c] + x1 * W[3][1][c] + x2 * W[3][2][c] + x3 * W[3][3][c] + B[3][c];
  q[n * 128 + c] = qv;
  kvb[(size_t)n * 256 + c]       = f2bf(kv);
  kvb[(size_t)n * 256 + 128 + c] = f2bf(vv);
  hs[n * 128 + c] = sv;
}

// ============== W -> bf16 transposed: wt[z][c][k] = W_z[k][c] =============
__global__ void prep_w(const float* __restrict__ Wq, const float* __restrict__ Wk,
                       const float* __restrict__ Wv, const float* __restrict__ Ws,
                       ushort* __restrict__ wt) {
  int idx = blockIdx.x * 256 + threadIdx.x;  // 4*16384
  int z = idx >> 14, rem = idx & 16383;
  int k_ = rem >> 7, c_ = rem & 127;
  const float* W = (z == 0) ? Wq : (z == 1) ? Wk : (z == 2) ? Wv : Ws;
  wt[z * 16384 + c_ * 128 + k_] = f2bf(W[k_ * 128 + c_]);
}

// ============ layers 1-2 GEMM via MFMA: [N,128] @ [128,128] ==============
#define LDA 136
__global__ __launch_bounds__(256) void gemm_mfma(
    const float* __restrict__ H, const ushort* __restrict__ wtg,
    const float* __restrict__ bq, const float* __restrict__ bk,
    const float* __restrict__ bv, const float* __restrict__ bs,
    float* __restrict__ q, ushort* __restrict__ kvb,
    float* __restrict__ hs, int N) {
  int z = blockIdx.z;
  const float* bb = (z == 0) ? bq : (z == 1) ? bk : (z == 2) ? bv : bs;
  __shared__ ushort Alds[64 * LDA];
  __shared__ ushort Wlds[128 * LDA];
  int tid = threadIdx.x;
  int n0 = blockIdx.x * 64;

  {
    const uint* wg = (const uint*)(wtg + z * 16384);
    uint* wl = (uint*)Wlds;
    for (int i = tid; i < 8192; i += 256) {
      int c_ = i >> 6, kp = i & 63;
      wl[c_ * (LDA / 2) + kp] = wg[c_ * 64 + kp];
    }
  }
  {
    uint* al = (uint*)Alds;
    for (int i = tid; i < 4096; i += 256) {
      int r = i >> 6, kp = i & 63;
      int grow = n0 + r; grow = (grow < N) ? grow : (N - 1);
      float2 hv = *(const float2*)&H[(size_t)grow * 128 + 2 * kp];
      al[r * (LDA / 2) + kp] = (uint)f2bf(hv.x) | ((uint)f2bf(hv.y) << 16);
    }
  }
  __syncthreads();

  int w = tid >> 6, lane = tid & 63;
  int m_ = lane & 15, quad = lane >> 4;
  f32x4 acc[8];
#pragma unroll
  for (int ct = 0; ct < 8; ct++) acc[ct] = 0.f;

#pragma unroll
  for (int kc = 0; kc < 4; kc++) {
    short8 af = *(const short8*)&Alds[(w * 16 + m_) * LDA + kc * 32 + quad * 8];
#pragma unroll
    for (int ct = 0; ct < 8; ct++) {
      short8 bf = *(const short8*)&Wlds[(ct * 16 + m_) * LDA + kc * 32 + quad * 8];
      acc[ct] = __builtin_amdgcn_mfma_f32_16x16x32_bf16(af, bf, acc[ct], 0, 0, 0);
    }
  }

#pragma unroll
  for (int ct = 0; ct < 8; ct++) {
    int col = ct * 16 + m_;
    float bcol = bb[col];
#pragma unroll
    for (int reg = 0; reg < 4; reg++) {
      int n = n0 + w * 16 + quad * 4 + reg;
      if (n < N) {
        float o = acc[ct][reg] + bcol;
        if (z == 0)      q[(size_t)n * 128 + col] = o;
        else if (z == 3) hs[(size_t)n * 128 + col] = o;
        else             kvb[(size_t)n * 256 + ((z == 2) ? 128 : 0) + col] = f2bf(o);
      }
    }
  }
}

// ====== fused attention v4: sw-pipelined gathers, 2 edges/group/iter ======
__global__ __launch_bounds__(256) void attn_fused(
    const float* __restrict__ q, const ushort* __restrict__ kv,
    const int* __restrict__ indptr, const int* __restrict__ csr_src,
    const float4* __restrict__ csr_attr, const float* __restrict__ We,
    float* __restrict__ h, int N) {
  __shared__ float WeS[384];
  int tid = threadIdx.x;
  for (int i = tid; i < 384; i += 256) WeS[i] = We[i];
  __syncthreads();
  int lane = tid & 63;
  int n = blockIdx.x * 4 + (tid >> 6);
  if (n >= N) return;
  int g = lane >> 4, gl = lane & 15;
  int c = gl * 8;  // 8 channels per lane
  float4 qa  = *(const float4*)&q[(size_t)n * 128 + c];
  float4 qb4 = *(const float4*)&q[(size_t)n * 128 + c + 4];
  float qv[8] = {qa.x, qa.y, qa.z, qa.w, qb4.x, qb4.y, qb4.z, qb4.w};

  // t = We^T q  (identical across the 4 groups after 16-lane reduce)
  float t0 = 0.f, t1 = 0.f, t2 = 0.f;
#pragma unroll
  for (int j = 0; j < 8; j++) {
    t0 = fmaf(WeS[c + j], qv[j], t0);
    t1 = fmaf(WeS[128 + c + j], qv[j], t1);
    t2 = fmaf(WeS[256 + c + j], qv[j], t2);
  }
#pragma unroll
  for (int off = 1; off < 16; off <<= 1) {
    t0 += __shfl_xor(t0, off);
    t1 += __shfl_xor(t1, off);
    t2 += __shfl_xor(t2, off);
  }

  float4 sk0 = *(const float4*)&h[(size_t)n * 128 + c];
  float4 sk1 = *(const float4*)&h[(size_t)n * 128 + c + 4];
  int beg = indptr[n], end = indptr[n + 1];

  if (end > beg) {
    float m = -3.4e38f, d = 0.f;
    float sa0 = 0.f, sa1 = 0.f, sa2 = 0.f;
    float acc[8];
#pragma unroll
    for (int j = 0; j < 8; j++) acc[j] = 0.f;

    const uint4* kv4 = (const uint4*)kv;  // 32 x uint4 per node (k:0..15, v:16..31)
    float4 zf = make_float4(0.f, 0.f, 0.f, 0.f);

    int i = beg + g;
    // ---- pipeline prologue: indices+attr, then kv loads ----
    int sjn1 = 0, sjn2 = 0;
    float4 atn1 = zf, atn2 = zf;
    {
      bool p1 = i < end, p2 = (i + 4) < end;
      if (p1) { sjn1 = csr_src[i]; atn1 = csr_attr[i]; }
      if (p2) { sjn2 = csr_src[i + 4]; atn2 = csr_attr[i + 4]; }
    }
    uint4 kr1 = kv4[(size_t)sjn1 * 32 + gl];
    uint4 vr1 = kv4[(size_t)sjn1 * 32 + 16 + gl];
    uint4 kr2 = kv4[(size_t)sjn2 * 32 + gl];
    uint4 vr2 = kv4[(size_t)sjn2 * 32 + 16 + gl];

    for (; i < end; i += 8) {
      // capture current stage
      uint4 kc1 = kr1, vc1 = vr1, kc2 = kr2, vc2 = vr2;
      float4 a1c = atn1, a2c = atn2;
      bool c2 = (i + 4) < end;

      // prefetch next stage (indices then kv)
      int in_ = i + 8;
      bool fn1 = in_ < end, fn2 = (in_ + 4) < end;
      sjn1 = 0; sjn2 = 0;
      if (fn1) { sjn1 = csr_src[in_]; atn1 = csr_attr[in_]; }
      if (fn2) { sjn2 = csr_src[in_ + 4]; atn2 = csr_attr[in_ + 4]; }
      kr1 = kv4[(size_t)sjn1 * 32 + gl];
      vr1 = kv4[(size_t)sjn1 * 32 + 16 + gl];
      kr2 = kv4[(size_t)sjn2 * 32 + gl];
      vr2 = kv4[(size_t)sjn2 * 32 + 16 + gl];

      // ---- process edge A ----
      float vA[8], vB[8];
      float pA = 0.f, pB = 0.f;
      {
        float kx[8];
        kx[0] = bflo(kc1.x); kx[1] = bfhi(kc1.x); kx[2] = bflo(kc1.y); kx[3] = bfhi(kc1.y);
        kx[4] = bflo(kc1.z); kx[5] = bfhi(kc1.z); kx[6] = bflo(kc1.w); kx[7] = bfhi(kc1.w);
#pragma unroll
        for (int j = 0; j < 8; j++) pA = fmaf(qv[j], kx[j], pA);
      }
      {
        float kx[8];
        kx[0] = bflo(kc2.x); kx[1] = bfhi(kc2.x); kx[2] = bflo(kc2.y); kx[3] = bfhi(kc2.y);
        kx[4] = bflo(kc2.z); kx[5] = bfhi(kc2.z); kx[6] = bflo(kc2.w); kx[7] = bfhi(kc2.w);
#pragma unroll
        for (int j = 0; j < 8; j++) pB = fmaf(qv[j], kx[j], pB);
      }
      pA += __shfl_xor(pA, 1); pA += __shfl_xor(pA, 2);
      pA += __shfl_xor(pA, 4); pA += __shfl_xor(pA, 8);
      pB += __shfl_xor(pB, 1); pB += __shfl_xor(pB, 2);
      pB += __shfl_xor(pB, 4); pB += __shfl_xor(pB, 8);
      pA = fmaf(a1c.x, t0, pA); pA = fmaf(a1c.y, t1, pA); pA = fmaf(a1c.z, t2, pA);
      pB = fmaf(a2c.x, t0, pB); pB = fmaf(a2c.y, t1, pB); pB = fmaf(a2c.z, t2, pB);
      float lA = pA * 0.08838834764831845f;
      float lB = c2 ? (pB * 0.08838834764831845f) : -3.4e38f;

      vA[0] = bflo(vc1.x); vA[1] = bfhi(vc1.x); vA[2] = bflo(vc1.y); vA[3] = bfhi(vc1.y);
      vA[4] = bflo(vc1.z); vA[5] = bfhi(vc1.z); vA[6] = bflo(vc1.w); vA[7] = bfhi(vc1.w);
      vB[0] = bflo(vc2.x); vB[1] = bfhi(vc2.x); vB[2] = bflo(vc2.y); vB[3] = bfhi(vc2.y);
      vB[4] = bflo(vc2.z); vB[5] = bfhi(vc2.z); vB[6] = bflo(vc2.w); vB[7] = bfhi(vc2.w);

      // pairwise online-softmax update (exact reassociation)
      float nm = fmaxf(m, fmaxf(lA, lB));
      float sf = __expf(m - nm);
      float aA = __expf(lA - nm);
      float aB = __expf(lB - nm);
      d = d * sf + aA + aB;
      sa0 = sa0 * sf + aA * a1c.x + aB * a2c.x;
      sa1 = sa1 * sf + aA * a1c.y + aB * a2c.y;
      sa2 = sa2 * sf + aA * a1c.z + aB * a2c.z;
#pragma unroll
      for (int j = 0; j < 8; j++)
        acc[j] = acc[j] * sf + aA * vA[j] + aB * vB[j];
      m = nm;
    }

    // merge the 4 groups' online-softmax states
#pragma unroll
    for (int off = 16; off < 64; off <<= 1) {
      float m2 = __shfl_xor(m, off);
      float d2 = __shfl_xor(d, off);
      float nm = fmaxf(m, m2);
      float s1 = __expf(m - nm), s2 = __expf(m2 - nm);
      d = d * s1 + d2 * s2;
      sa0 = sa0 * s1 + __shfl_xor(sa0, off) * s2;
      sa1 = sa1 * s1 + __shfl_xor(sa1, off) * s2;
      sa2 = sa2 * s1 + __shfl_xor(sa2, off) * s2;
#pragma unroll
      for (int j = 0; j < 8; j++) {
        float a2 = __shfl_xor(acc[j], off);
        acc[j] = acc[j] * s1 + a2 * s2;
      }
      m = nm;
    }
    float inv = 1.f / d;
    float o[8];
#pragma unroll
    for (int j = 0; j < 8; j++) {
      float ecorr = sa0 * WeS[c + j] + sa1 * WeS[128 + c + j] + sa2 * WeS[256 + c + j];
      o[j] = (acc[j] + ecorr) * inv;
    }
    sk0.x += o[0]; sk0.y += o[1]; sk0.z += o[2]; sk0.w += o[3];
    sk1.x += o[4]; sk1.y += o[5]; sk1.z += o[6]; sk1.w += o[7];
  }
  sk0.x = (sk0.x > 0.f) ? sk0.x : 0.01f * sk0.x;
  sk0.y = (sk0.y > 0.f) ? sk0.y : 0.01f * sk0.y;
  sk0.z = (sk0.z > 0.f) ? sk0.z : 0.01f * sk0.z;
  sk0.w = (sk0.w > 0.f) ? sk0.w : 0.01f * sk0.w;
  sk1.x = (sk1.x > 0.f) ? sk1.x : 0.01f * sk1.x;
  sk1.y = (sk1.y > 0.f) ? sk1.y : 0.01f * sk1.y;
  sk1.z = (sk1.z > 0.f) ? sk1.z : 0.01f * sk1.z;
  sk1.w = (sk1.w > 0.f) ? sk1.w : 0.01f * sk1.w;
  if (g == 0) {
    *(float4*)&h[(size_t)n * 128 + c] = sk0;
    *(float4*)&h[(size_t)n * 128 + c + 4] = sk1;
  }
}

// ======================= pool (batch is sorted) ==========================
__global__ void pool_kernel(const float* __restrict__ h, const int* __restrict__ batch,
                            float* __restrict__ gout, int N) {
  int tid = threadIdx.x;
  int sub = tid >> 6;
  int c = 2 * (tid & 63);
  int n0 = blockIdx.x * 64 + sub * 16;
  if (n0 >= N) return;
  int n1 = min(n0 + 16, N);
  float a0 = 0.f, a1 = 0.f;
  int cur = batch[n0];
  for (int n = n0; n < n1; n++) {
    int b = batch[n];
    if (b != cur) {
      atomicAdd(&gout[cur * 128 + c], a0);
      atomicAdd(&gout[cur * 128 + c + 1], a1);
      a0 = 0.f; a1 = 0.f; cur = b;
    }
    float2 hv = *(const float2*)&h[(size_t)n * 128 + c];
    a0 += hv.x; a1 += hv.y;
  }
  atomicAdd(&gout[cur * 128 + c], a0);
  atomicAdd(&gout[cur * 128 + c + 1], a1);
}

// ===================== fused MLP head (one block / graph) ================
__global__ __launch_bounds__(256) void mlp_fused(
    const float* __restrict__ gp,
    const float* __restrict__ Wl0, const float* __restrict__ bl0,
    const float* __restrict__ Wl1, const float* __restrict__ bl1,
    const float* __restrict__ Wl2, const float* __restrict__ bl2,
    float* __restrict__ out) {
  int g = blockIdx.x;
  int tid = threadIdx.x;
  __shared__ float xin[CDIM];
  __shared__ float h1[L0DIM];
  __shared__ float h2[L1DIM];
  __shared__ float r0s[4], r1s[4];
  if (tid < CDIM) xin[tid] = gp[g * CDIM + tid];
  __syncthreads();
  for (int c = tid; c < L0DIM; c += 256) {
    float a0 = 0.f, a1 = 0.f, a2 = 0.f, a3 = 0.f;
#pragma unroll 4
    for (int kk = 0; kk < CDIM; kk += 4) {
      a0 = fmaf(xin[kk + 0], Wl0[(kk + 0) * L0DIM + c], a0);
      a1 = fmaf(xin[kk + 1], Wl0[(kk + 1) * L0DIM + c], a1);
      a2 = fmaf(xin[kk + 2], Wl0[(kk + 2) * L0DIM + c], a2);
      a3 = fmaf(xin[kk + 3], Wl0[(kk + 3) * L0DIM + c], a3);
    }
    h1[c] = fmaxf((a0 + a1) + (a2 + a3) + bl0[c], 0.f);
  }
  __syncthreads();
  {
    int c = tid;
    float a0 = 0.f, a1 = 0.f, a2 = 0.f, a3 = 0.f;
#pragma unroll 4
    for (int kk = 0; kk < L0DIM; kk += 4) {
      a0 = fmaf(h1[kk + 0], Wl1[(kk + 0) * L1DIM + c], a0);
      a1 = fmaf(h1[kk + 1], Wl1[(kk + 1) * L1DIM + c], a1);
      a2 = fmaf(h1[kk + 2], Wl1[(kk + 2) * L1DIM + c], a2);
      a3 = fmaf(h1[kk + 3], Wl1[(kk + 3) * L1DIM + c], a3);
    }
    h2[c] = fmaxf((a0 + a1) + (a2 + a3) + bl1[c], 0.f);
  }
  __syncthreads();
  float p0 = h2[tid] * Wl2[tid * 2 + 0];
  float p1 = h2[tid] * Wl2[tid * 2 + 1];
#pragma unroll
  for (int off = 32; off > 0; off >>= 1) {
    p0 += __shfl_down(p0, off);
    p1 += __shfl_down(p1, off);
  }
  int wv = tid >> 6, ln = tid & 63;
  if (ln == 0) { r0s[wv] = p0; r1s[wv] = p1; }
  __syncthreads();
  if (tid == 0) out[g * 2 + 0] = r0s[0] + r0s[1] + r0s[2] + r0s[3] + bl2[0];
  if (tid == 1) out[g * 2 + 1] = r1s[0] + r1s[1] + r1s[2] + r1s[3] + bl2[1];
}

// ============================== launch ==================================
extern "C" void kernel_launch(void* const* d_in, const int* in_sizes, int n_in,
                              void* d_out, int out_size, void* d_ws, size_t ws_size,
                              hipStream_t stream) {
  const int N = N_NODES, E = N_EDGES;
  const float* x    = (const float*)d_in[0];
  const int*   ei   = (const int*)d_in[1];
  const float* attr = (const float*)d_in[2];
  const int*   batch= (const int*)d_in[3];
  const int* src = ei;
  const int* dst = ei + E;

  const float *Wq0 = (const float*)d_in[4],  *bq0 = (const float*)d_in[5];
  const float *Wk0 = (const float*)d_in[6],  *bk0 = (const float*)d_in[7];
  const float *Wv0 = (const float*)d_in[8],  *bv0 = (const float*)d_in[9];
  const float *We0 = (const float*)d_in[10];
  const float *Ws0 = (const float*)d_in[11], *bs0 = (const float*)d_in[12];
  const float *Wq1 = (const float*)d_in[13], *bq1 = (const float*)d_in[14];
  const float *Wk1 = (const float*)d_in[15], *bk1 = (const float*)d_in[16];
  const float *Wv1 = (const float*)d_in[17], *bv1 = (const float*)d_in[18];
  const float *We1 = (const float*)d_in[19];
  const float *Ws1 = (const float*)d_in[20], *bs1 = (const float*)d_in[21];
  const float *Wl0 = (const float*)d_in[22], *bl0 = (const float*)d_in[23];
  const float *Wl1 = (const float*)d_in[24], *bl1 = (const float*)d_in[25];
  const float *Wl2 = (const float*)d_in[26], *bl2 = (const float*)d_in[27];

  size_t off = 0;
  auto carve = [&](size_t bytes) {
    void* p = (char*)d_ws + off;
    off += (bytes + 255) & ~(size_t)255;
    return p;
  };
  float*  hA       = (float*)carve((size_t)N * CDIM * 4);
  float*  hB       = (float*)carve((size_t)N * CDIM * 4);
  float*  qb       = (float*)carve((size_t)N * CDIM * 4);
  ushort* kvb      = (ushort*)carve((size_t)N * 256 * 2);
  int*    indptr   = (int*)carve((size_t)(N + 1) * 4);
  int*    csr_src  = (int*)carve((size_t)E * 4);
  float4* csr_attr = (float4*)carve((size_t)E * 16);
  int*    cc       = (int*)carve((size_t)2 * N * 4);   // counts | cursor
  int*    counts   = cc;
  int*    cursor   = cc + N;
  int*    excl     = (int*)carve((size_t)N * 4);
  int*    bsums    = (int*)carve((size_t)64 * 4);
  ushort* wt1      = (ushort*)carve((size_t)4 * 16384 * 2);
  float*  gp       = (float*)carve((size_t)GDIM * CDIM * 4);

  hipMemsetAsync(cc, 0, (size_t)2 * N * 4, stream);
  hipMemsetAsync(gp, 0, (size_t)GDIM * CDIM * 4, stream);

  int nscan = (N + 1023) / 1024;
  hist_kernel<<<(E + 255) / 256, 256, 0, stream>>>(dst, counts, E);
  scan_blocks<<<nscan, 1024, 0, stream>>>(counts, excl, bsums, N);
  scan_sums<<<1, 64, 0, stream>>>(bsums, nscan);
  scan_add<<<nscan, 1024, 0, stream>>>(excl, bsums, indptr, N, E);
  scatter2_kernel<<<(E + 255) / 256, 256, 0, stream>>>(dst, src, attr, indptr, cursor,
                                                       csr_src, csr_attr, E);
  prep_w<<<256, 256, 0, stream>>>(Wq1, Wk1, Wv1, Ws1, wt1);

  int naBlocks = (N + 3) / 4;
  dim3 gemmGrid((N + 63) / 64, 1, 4);

  // ---- layer 0 (din=4) ----
  l0_qkvs<<<(N * 128 + 255) / 256, 256, 0, stream>>>(
      x, Wq0, bq0, Wk0, bk0, Wv0, bv0, Ws0, bs0, qb, kvb, hA, N);
  attn_fused<<<naBlocks, 256, 0, stream>>>(qb, kvb, indptr, csr_src, csr_attr, We0, hA, N);

  // ---- layer 1 (shared weights) ----
  gemm_mfma<<<gemmGrid, 256, 0, stream>>>(hA, wt1, bq1, bk1, bv1, bs1, qb, kvb, hB, N);
  attn_fused<<<naBlocks, 256, 0, stream>>>(qb, kvb, indptr, csr_src, csr_attr, We1, hB, N);

  // ---- layer 2 (same weights) ----
  gemm_mfma<<<gemmGrid, 256, 0, stream>>>(hB, wt1, bq1, bk1, bv1, bs1, qb, kvb, hA, N);
  attn_fused<<<naBlocks, 256, 0, stream>>>(qb, kvb, indptr, csr_src, csr_attr, We1, hA, N);

  // ---- pool + fused MLP ----
  pool_kernel<<<(N + 63) / 64, 256, 0, stream>>>(hA, batch, gp, N);
  mlp_fused<<<GDIM, 256, 0, stream>>>(gp, Wl0, bl0, Wl1, bl1, Wl2, bl2, (float*)d_out);
}